// Round 3
// baseline (79.994 us; speedup 1.0000x reference)
//
#include <hip/hip_runtime.h>
#include <hip/hip_bf16.h>

// GaussianVoxelizer: B=1, G=128 gaussians, F=16 features, N=80000 voxels.
// Sum/count formulation (== reference's incremental masked mean).
//
// R3 design: kill the LDS-throughput bottleneck. Gaussian params are
// wave-uniform -> move them to SGPRs via scalar loads. A tiny prep kernel
// packs per-gaussian {mean, opacity, -0.5*inv_cov (off-diags pre-doubled),
// opacity*features} into d_ws as 7 float4s; the main kernel indexes them
// with a uniform loop counter so the compiler emits s_load (scalar pipe,
// parallel to VALU). Hot loop: ~13 VALU ops, zero LDS.
//
// Inputs (setup_inputs order):
//   d_in[0] grid_coords (N,3) f32
//   d_in[1] means3d     (1,G,3) f32
//   d_in[2] opacities   (1,G,1) f32
//   d_in[3] features    (1,G,F) f32
//   d_in[4] covariances (1,G,3,3) f32
// Output: dens (N) f32 followed by feats (N,F) f32, concatenated flat.

#define GV_F 16
#define GV_NV 64          // voxels per block
#define GV_NW 4           // waves per block (G split 4 ways)
#define GV_RW (GV_F + 2)  // per-voxel partial: cnt, dens, 16 feats
#define GV_Q 7            // float4s per gaussian in packed params

__global__ __launch_bounds__(128)
void gv_prep(const float* __restrict__ means,  // (G,3)
             const float* __restrict__ opac,   // (G)
             const float* __restrict__ feats,  // (G,F)
             const float* __restrict__ covs,   // (G,9)
             float4* __restrict__ P,           // (G, GV_Q) float4
             int G)
{
    const int g = blockIdx.x * blockDim.x + threadIdx.x;
    if (g >= G) return;

    const float c00 = covs[g * 9 + 0];
    const float c01 = covs[g * 9 + 1];
    const float c02 = covs[g * 9 + 2];
    const float c11 = covs[g * 9 + 4];
    const float c12 = covs[g * 9 + 5];
    const float c22 = covs[g * 9 + 8];
    // cofactors (cov = A*A^T + 0.1I is SPD, det >= 1e-3)
    const float m00 = c11 * c22 - c12 * c12;
    const float m01 = c02 * c12 - c01 * c22;
    const float m02 = c01 * c12 - c02 * c11;
    const float det = c00 * m00 + c01 * m01 + c02 * m02;
    const float s = -0.5f / det;   // fold the -0.5 of exp(-0.5*maha) in here
    // k: coefficients of t = -0.5*maha; off-diagonals pre-doubled
    const float k00 = m00 * s;
    const float k01 = m01 * (2.0f * s);
    const float k02 = m02 * (2.0f * s);
    const float k11 = (c00 * c22 - c02 * c02) * s;
    const float k12 = (c01 * c02 - c00 * c12) * (2.0f * s);
    const float k22 = (c00 * c11 - c01 * c01) * s;

    const float op = opac[g];
    float4* q = P + (size_t)g * GV_Q;
    q[0] = make_float4(means[g * 3 + 0], means[g * 3 + 1], means[g * 3 + 2], op);
    q[1] = make_float4(k00, k01, k02, k11);
    q[2] = make_float4(k12, k22, 0.0f, 0.0f);
    #pragma unroll
    for (int j = 0; j < 4; ++j) {
        q[3 + j] = make_float4(op * feats[g * GV_F + 4 * j + 0],
                               op * feats[g * GV_F + 4 * j + 1],
                               op * feats[g * GV_F + 4 * j + 2],
                               op * feats[g * GV_F + 4 * j + 3]);
    }
}

__global__ __launch_bounds__(256)
void GaussianVoxelizer_40467181863368_kernel(
    const float* __restrict__ grid,    // (N,3)
    const float4* __restrict__ P,      // (G, GV_Q) packed params
    float* __restrict__ out_dens,      // (N)
    float* __restrict__ out_feat,      // (N,F)
    int N, int G)
{
    __shared__ float s_red[GV_NW][GV_NV][GV_RW];

    const int t = threadIdx.x;
    const int wave = t >> 6;
    const int lane = t & 63;
    const int n = blockIdx.x * GV_NV + lane;

    float px = 0.0f, py = 0.0f, pz = 0.0f;
    if (n < N) {
        px = grid[n * 3 + 0];
        py = grid[n * 3 + 1];
        pz = grid[n * 3 + 2];
    }

    const int chunk = (G + GV_NW - 1) / GV_NW;
    const int g0 = wave * chunk;
    const int g1 = (g0 + chunk < G) ? (g0 + chunk) : G;

    float cnt = 0.0f;
    float sum_d = 0.0f;
    float sum_f[GV_F];
    #pragma unroll
    for (int f = 0; f < GV_F; ++f) sum_f[f] = 0.0f;

    if (n < N) {
        #pragma unroll 4
        for (int g = g0; g < g1; ++g) {
            // g is wave-uniform -> these become s_load into SGPRs
            const float4 q0 = P[g * GV_Q + 0];
            const float4 q1 = P[g * GV_Q + 1];
            const float4 q2 = P[g * GV_Q + 2];
            const float dx = px - q0.x;
            const float dy = py - q0.y;
            const float dz = pz - q0.z;
            // t = -0.5 * maha (scales folded in prep)
            float a = q1.x * dx;
            a = fmaf(q1.y, dy, a);
            a = fmaf(q1.z, dz, a);
            float tt = a * dx;
            float b = q1.w * dy;
            b = fmaf(q2.x, dz, b);
            tt = fmaf(b, dy, tt);
            tt = fmaf(q2.y * dz, dz, tt);
            if (tt >= -2.0f) {           // maha <= 4.0
                const float w = __expf(tt);
                cnt += 1.0f;
                sum_d = fmaf(q0.w, w, sum_d);          // opacity * exp
                const float4 f0 = P[g * GV_Q + 3];
                const float4 f1 = P[g * GV_Q + 4];
                const float4 f2 = P[g * GV_Q + 5];
                const float4 f3 = P[g * GV_Q + 6];
                sum_f[0]  = fmaf(f0.x, w, sum_f[0]);
                sum_f[1]  = fmaf(f0.y, w, sum_f[1]);
                sum_f[2]  = fmaf(f0.z, w, sum_f[2]);
                sum_f[3]  = fmaf(f0.w, w, sum_f[3]);
                sum_f[4]  = fmaf(f1.x, w, sum_f[4]);
                sum_f[5]  = fmaf(f1.y, w, sum_f[5]);
                sum_f[6]  = fmaf(f1.z, w, sum_f[6]);
                sum_f[7]  = fmaf(f1.w, w, sum_f[7]);
                sum_f[8]  = fmaf(f2.x, w, sum_f[8]);
                sum_f[9]  = fmaf(f2.y, w, sum_f[9]);
                sum_f[10] = fmaf(f2.z, w, sum_f[10]);
                sum_f[11] = fmaf(f2.w, w, sum_f[11]);
                sum_f[12] = fmaf(f3.x, w, sum_f[12]);
                sum_f[13] = fmaf(f3.y, w, sum_f[13]);
                sum_f[14] = fmaf(f3.z, w, sum_f[14]);
                sum_f[15] = fmaf(f3.w, w, sum_f[15]);
            }
        }
    }

    // ---- per-wave partials -> LDS ----
    {
        float* r = &s_red[wave][lane][0];
        r[0] = cnt;
        r[1] = sum_d;
        #pragma unroll
        for (int f = 0; f < GV_F; ++f) r[2 + f] = sum_f[f];
    }
    __syncthreads();

    // ---- reduce across the 4 waves; threads 0..63 finalize one voxel each ----
    if (t < GV_NV) {
        const int n2 = blockIdx.x * GV_NV + t;
        if (n2 < N) {
            float c = 0.0f, d = 0.0f;
            float ff[GV_F];
            #pragma unroll
            for (int f = 0; f < GV_F; ++f) ff[f] = 0.0f;
            #pragma unroll
            for (int w = 0; w < GV_NW; ++w) {
                const float* r = &s_red[w][t][0];
                c += r[0];
                d += r[1];
                #pragma unroll
                for (int f = 0; f < GV_F; ++f) ff[f] += r[2 + f];
            }
            const float inv_c = (c > 0.0f) ? (1.0f / c) : 0.0f;
            out_dens[n2] = d * inv_c;
            float4* fo = (float4*)(out_feat + (size_t)n2 * GV_F);
            #pragma unroll
            for (int q = 0; q < 4; ++q) {
                fo[q] = make_float4(ff[4 * q + 0] * inv_c,
                                    ff[4 * q + 1] * inv_c,
                                    ff[4 * q + 2] * inv_c,
                                    ff[4 * q + 3] * inv_c);
            }
        }
    }
}

extern "C" void kernel_launch(void* const* d_in, const int* in_sizes, int n_in,
                              void* d_out, int out_size, void* d_ws, size_t ws_size,
                              hipStream_t stream) {
    const float* grid  = (const float*)d_in[0];
    const float* means = (const float*)d_in[1];
    const float* opac  = (const float*)d_in[2];
    const float* feats = (const float*)d_in[3];
    const float* covs  = (const float*)d_in[4];

    const int N = in_sizes[0] / 3;       // 80000
    const int G = in_sizes[2];           // B*G = 128 (B=1)

    float4* P = (float4*)d_ws;           // (G, GV_Q) float4 = 14 KB

    float* out_dens = (float*)d_out;         // (N)
    float* out_feat = (float*)d_out + N;     // (N,F)

    gv_prep<<<(G + 127) / 128, 128, 0, stream>>>(means, opac, feats, covs, P, G);

    const int block = 256;
    const int grid_n = (N + GV_NV - 1) / GV_NV;   // 1250 blocks
    GaussianVoxelizer_40467181863368_kernel<<<grid_n, block, 0, stream>>>(
        grid, P, out_dens, out_feat, N, G);
}